// Round 1
// baseline (3717.315 us; speedup 1.0000x reference)
//
#include <hip/hip_runtime.h>

// ---------------- problem constants ----------------
#define NB    256
#define TLEN  1632
#define HIDC  64
#define CBD   512
#define NTOK  1024
#define T2L   816          // after enc conv1
#define T4L   408          // after enc conv2 (token count per batch)
#define MTOK  (NB*T4L)     // 104448 tokens
#define M2TOK (NB*T2L)     // 208896
#define MOUT  (NB*TLEN)    // 417792

// d_out flat offsets (floats)
#define DO_OUT    ((size_t)0)
#define DO_RECON  ((size_t)417792)
#define DO_COMMIT ((size_t)417793)
#define DO_IDX    ((size_t)417795)
#define DO_QUANT  ((size_t)626691)

// ---------------- workspace layout (float indices) ----------------
static constexpr size_t N_XR   = (size_t)MTOK * CBD;        // 53,477,376 (xr/residual; later d2buf)
static constexpr size_t OFF_XR = 0;
static constexpr size_t OFF_H1 = OFF_XR + N_XR;             // h1, later d1  [256*816*64]
static constexpr size_t N_H1   = (size_t)NB * T2L * HIDC;
static constexpr size_t OFF_H2 = OFF_H1 + N_H1;             // h2 [256*408*64]
static constexpr size_t N_H2   = (size_t)NB * T4L * HIDC;
static constexpr size_t OFF_BE2 = OFF_H2 + N_H2;            // 64*128
static constexpr size_t OFF_BD1 = OFF_BE2 + 8192;           // 128*512
static constexpr size_t OFF_BD2 = OFF_BD1 + 65536;          // 128*64
static constexpr size_t OFF_BX1 = OFF_BD2 + 8192;           // 128 expanded bias d1
static constexpr size_t OFF_BX2 = OFF_BX1 + 128;            // 128 expanded bias d2
static constexpr size_t OFF_C2  = OFF_BX2 + 128;            // 2048 codebook norms
static constexpr size_t OFF_R2  = OFF_C2 + 2048;            // 104448 token norms
static constexpr size_t OFF_SLOT= OFF_R2 + MTOK;            // 1536 loss slots (recon, c0, c1)
static constexpr size_t OFF_IDXI= OFF_SLOT + 1536;          // 104448*2 ints
static constexpr size_t OFF_KEYS= OFF_IDXI + (size_t)MTOK*2;// 2*104448 u64 (even float offset -> 8B aligned)

// ---------------- helpers ----------------
__device__ inline unsigned long long shfl_xor_u64(unsigned long long v, int m) {
    unsigned lo = (unsigned)v, hi = (unsigned)(v >> 32);
    lo = __shfl_xor(lo, m, 64);
    hi = __shfl_xor(hi, m, 64);
    return (((unsigned long long)hi) << 32) | lo;
}

// ---------------- weight prep ----------------
__global__ void prep_kernel(const float* __restrict__ We2, const float* __restrict__ Wtd1,
                            const float* __restrict__ Wtd2, const float* __restrict__ bd1,
                            const float* __restrict__ bd2,
                            float* __restrict__ Be2, float* __restrict__ Bd1,
                            float* __restrict__ Bd2, float* __restrict__ bx1, float* __restrict__ bx2) {
    int i = blockIdx.x * blockDim.x + threadIdx.x;
    int stride = gridDim.x * blockDim.x;
    // Be2[c][k], k = tap*64 + ch  ->  We2[c][ch][tap]
    for (int x = i; x < 64 * 128; x += stride) {
        int c = x >> 7, k = x & 127;
        Be2[x] = We2[c * 128 + ((k & 63) << 1) + (k >> 6)];
    }
    // Bd1[n][k] = Wtd1[k*128 + n]   (n = co*2+tap, k = ci)
    for (int x = i; x < 128 * 512; x += stride) {
        int n = x >> 9, k = x & 511;
        Bd1[x] = Wtd1[k * 128 + n];
    }
    // Bd2[n][k] = Wtd2[k*128 + n]
    for (int x = i; x < 128 * 64; x += stride) {
        int n = x >> 6, k = x & 63;
        Bd2[x] = Wtd2[k * 128 + n];
    }
    for (int x = i; x < 128; x += stride) { bx1[x] = bd1[x >> 1]; bx2[x] = bd2[x >> 1]; }
}

// ---------------- row sum-of-squares (512-wide rows): one wave per row ----------------
__global__ void rownorm_kernel(const float* __restrict__ X, float* __restrict__ out, int rows) {
    int w = (blockIdx.x * blockDim.x + threadIdx.x) >> 6;
    int lane = threadIdx.x & 63;
    if (w >= rows) return;
    const float* r = X + (size_t)w * 512;
    float4 a = *(const float4*)(r + lane * 8);
    float4 b = *(const float4*)(r + lane * 8 + 4);
    float s = a.x*a.x + a.y*a.y + a.z*a.z + a.w*a.w + b.x*b.x + b.y*b.y + b.z*b.z + b.w*b.w;
    #pragma unroll
    for (int o = 32; o > 0; o >>= 1) s += __shfl_down(s, o, 64);
    if (lane == 0) out[w] = s;
}

// ---------------- encoder conv1 (Cin=1, k2s2) -> h1 token-major [b][t][c] ----------------
__global__ void enc1_kernel(const float* __restrict__ img, const float* __restrict__ W,
                            const float* __restrict__ bias, float* __restrict__ h1) {
    int idx = blockIdx.x * 256 + threadIdx.x;          // over 256*816*64
    int c = idx & 63;
    int t = (idx >> 6) % T2L;
    int b = idx / (64 * T2L);
    float v = W[c * 2] * img[(size_t)b * TLEN + 2 * t] +
              W[c * 2 + 1] * img[(size_t)b * TLEN + 2 * t + 1] + bias[c];
    h1[idx] = fmaxf(v, 0.f);
}

// ---------------- generic NT SGEMM: C[M,N] = A[M,K] . B[N,K]^T + bias ----------------
// tile 128(M) x 64(N), K-chunk 32, 256 threads, 8x4 microtile
// amode: 0 plain row-major A (ld=K); 1 e2 concat-token view of h1; 2 channel-major quantized
// cmode: 0 C[m*N+n]; 1 convT1 interleave (Tin=408); 2 convT2 interleave (Tin=816)
__global__ __launch_bounds__(256) void gemm_nt(const float* __restrict__ A, const float* __restrict__ Bw,
                        const float* __restrict__ bias, float* __restrict__ C,
                        int M, int N, int K, int amode, int cmode, int relu) {
    __shared__ float As[32][132];
    __shared__ float Bs[32][68];
    int m0 = blockIdx.x * 128;
    int n0 = blockIdx.y * 64;
    int tid = threadIdx.x;
    int tx = tid & 15;
    int ty = tid >> 4;
    float acc[8][4];
    #pragma unroll
    for (int i = 0; i < 8; ++i)
        #pragma unroll
        for (int j = 0; j < 4; ++j) acc[i][j] = 0.f;

    for (int k0 = 0; k0 < K; k0 += 32) {
        if (amode != 2) {
            #pragma unroll
            for (int i = 0; i < 4; ++i) {
                int idx = tid + i * 256;           // 0..1023
                int row = idx >> 3;
                int kq = idx & 7;
                int m = m0 + row;
                size_t base;
                if (amode == 0) base = (size_t)m * K;
                else            base = (size_t)(((m / T4L) * T2L + 2 * (m % T4L)) * 64);
                float4 v = *(const float4*)(A + base + k0 + kq * 4);
                int kk = kq * 4;
                As[kk + 0][row] = v.x; As[kk + 1][row] = v.y;
                As[kk + 2][row] = v.z; As[kk + 3][row] = v.w;
            }
        } else {
            // quantized channel-major: addr = ((m/408)*512 + k)*408 + (m%408)
            int ml = tid & 127;
            int kl = tid >> 7;                     // 0..1
            int m = m0 + ml;
            int b = m / T4L, t = m % T4L;
            size_t rowbase = ((size_t)b * 512) * T4L + t;
            for (int kk = kl; kk < 32; kk += 2)
                As[kk][ml] = A[rowbase + (size_t)(k0 + kk) * T4L];
        }
        #pragma unroll
        for (int i = 0; i < 2; ++i) {
            int idx = tid + i * 256;               // 0..511
            int row = idx >> 3;
            int kq = idx & 7;
            float4 v = *(const float4*)(Bw + (size_t)(n0 + row) * K + k0 + kq * 4);
            int kk = kq * 4;
            Bs[kk + 0][row] = v.x; Bs[kk + 1][row] = v.y;
            Bs[kk + 2][row] = v.z; Bs[kk + 3][row] = v.w;
        }
        __syncthreads();
        #pragma unroll
        for (int kk = 0; kk < 32; ++kk) {
            float a[8], bf[4];
            float4 a0 = *(const float4*)&As[kk][ty * 8];
            float4 a1 = *(const float4*)&As[kk][ty * 8 + 4];
            a[0]=a0.x; a[1]=a0.y; a[2]=a0.z; a[3]=a0.w;
            a[4]=a1.x; a[5]=a1.y; a[6]=a1.z; a[7]=a1.w;
            float4 b0 = *(const float4*)&Bs[kk][tx * 4];
            bf[0]=b0.x; bf[1]=b0.y; bf[2]=b0.z; bf[3]=b0.w;
            #pragma unroll
            for (int i = 0; i < 8; ++i)
                #pragma unroll
                for (int j = 0; j < 4; ++j) acc[i][j] += a[i] * bf[j];
        }
        __syncthreads();
    }
    // epilogue
    #pragma unroll
    for (int i = 0; i < 8; ++i) {
        int m = m0 + ty * 8 + i;
        if (cmode == 0) {
            float4 v;
            float b0 = bias[n0 + tx * 4 + 0], b1 = bias[n0 + tx * 4 + 1];
            float b2 = bias[n0 + tx * 4 + 2], b3 = bias[n0 + tx * 4 + 3];
            v.x = acc[i][0] + b0; v.y = acc[i][1] + b1;
            v.z = acc[i][2] + b2; v.w = acc[i][3] + b3;
            if (relu) { v.x=fmaxf(v.x,0.f); v.y=fmaxf(v.y,0.f); v.z=fmaxf(v.z,0.f); v.w=fmaxf(v.w,0.f); }
            *(float4*)(C + (size_t)m * N + n0 + tx * 4) = v;
        } else {
            int Tin = (cmode == 1) ? T4L : T2L;
            int Texp = 2 * Tin;
            int bb = m / Tin, t = m % Tin;
            #pragma unroll
            for (int j = 0; j < 4; ++j) {
                int n = n0 + tx * 4 + j;
                float v = acc[i][j] + bias[n];
                if (relu) v = fmaxf(v, 0.f);
                size_t off = (size_t)((bb * Texp + 2 * t + (n & 1)) * 64 + (n >> 1));
                C[off] = v;
            }
        }
    }
}

// ---------------- VQ distance GEMM + argmin epilogue ----------------
// A = residual [MTOK,512], B = cb [1024,512]; d2 = (r2 - 2*dot) + c2; key=(map(d2)<<32)|n
__global__ __launch_bounds__(256) void vq_gemm_argmin(const float* __restrict__ A, const float* __restrict__ cb,
                               const float* __restrict__ c2, const float* __restrict__ r2,
                               unsigned long long* __restrict__ keybuf) {
    __shared__ float As[32][132];
    __shared__ float Bs[32][68];
    int m0 = blockIdx.x * 128;
    int n0 = blockIdx.y * 64;
    int tid = threadIdx.x;
    int tx = tid & 15;
    int ty = tid >> 4;
    float acc[8][4];
    #pragma unroll
    for (int i = 0; i < 8; ++i)
        #pragma unroll
        for (int j = 0; j < 4; ++j) acc[i][j] = 0.f;

    for (int k0 = 0; k0 < 512; k0 += 32) {
        #pragma unroll
        for (int i = 0; i < 4; ++i) {
            int idx = tid + i * 256;
            int row = idx >> 3;
            int kq = idx & 7;
            float4 v = *(const float4*)(A + (size_t)(m0 + row) * 512 + k0 + kq * 4);
            int kk = kq * 4;
            As[kk + 0][row] = v.x; As[kk + 1][row] = v.y;
            As[kk + 2][row] = v.z; As[kk + 3][row] = v.w;
        }
        #pragma unroll
        for (int i = 0; i < 2; ++i) {
            int idx = tid + i * 256;
            int row = idx >> 3;
            int kq = idx & 7;
            float4 v = *(const float4*)(cb + (size_t)(n0 + row) * 512 + k0 + kq * 4);
            int kk = kq * 4;
            Bs[kk + 0][row] = v.x; Bs[kk + 1][row] = v.y;
            Bs[kk + 2][row] = v.z; Bs[kk + 3][row] = v.w;
        }
        __syncthreads();
        #pragma unroll
        for (int kk = 0; kk < 32; ++kk) {
            float a[8], bf[4];
            float4 a0 = *(const float4*)&As[kk][ty * 8];
            float4 a1 = *(const float4*)&As[kk][ty * 8 + 4];
            a[0]=a0.x; a[1]=a0.y; a[2]=a0.z; a[3]=a0.w;
            a[4]=a1.x; a[5]=a1.y; a[6]=a1.z; a[7]=a1.w;
            float4 b0 = *(const float4*)&Bs[kk][tx * 4];
            bf[0]=b0.x; bf[1]=b0.y; bf[2]=b0.z; bf[3]=b0.w;
            #pragma unroll
            for (int i = 0; i < 8; ++i)
                #pragma unroll
                for (int j = 0; j < 4; ++j) acc[i][j] += a[i] * bf[j];
        }
        __syncthreads();
    }
    // argmin epilogue: reduce over this block's 64 codes per token, merge globally
    #pragma unroll
    for (int i = 0; i < 8; ++i) {
        int m = m0 + ty * 8 + i;
        float rr = r2[m];
        unsigned long long best = ~0ull;
        #pragma unroll
        for (int j = 0; j < 4; ++j) {
            int n = n0 + tx * 4 + j;
            float d2 = (rr - 2.0f * acc[i][j]) + c2[n];
            unsigned u = __float_as_uint(d2);
            u = (u & 0x80000000u) ? ~u : (u | 0x80000000u);   // monotonic map
            unsigned long long key = (((unsigned long long)u) << 32) | (unsigned)n;
            if (key < best) best = key;
        }
        #pragma unroll
        for (int s = 1; s < 16; s <<= 1) {
            unsigned long long o = shfl_xor_u64(best, s);
            if (o < best) best = o;
        }
        if (tx == 0) atomicMin(&keybuf[m], best);
    }
}

// ---------------- VQ apply: residual update, commit partial, indices ----------------
__global__ void vq_apply(const float* __restrict__ cb, const unsigned long long* __restrict__ keybuf,
                         float* __restrict__ R, float* __restrict__ r2,
                         float* __restrict__ idx_f, int* __restrict__ idx_i,
                         float* __restrict__ slots, int q, int write_r) {
    __shared__ float red[256];
    int m = blockIdx.x;
    int tid = threadIdx.x;
    unsigned idx = (unsigned)(keybuf[m] & 0xFFFFFFFFull);
    const float* c = cb + (size_t)idx * 512;
    float* r = R + (size_t)m * 512;
    float s = 0.f;
    for (int c0 = tid; c0 < 512; c0 += 256) {
        float nr = r[c0] - c[c0];
        if (write_r) r[c0] = nr;
        s += nr * nr;
    }
    red[tid] = s; __syncthreads();
    for (int st = 128; st > 0; st >>= 1) { if (tid < st) red[tid] += red[tid + st]; __syncthreads(); }
    if (tid == 0) {
        if (write_r) r2[m] = red[0];
        atomicAdd(&slots[512 + q * 512 + (m & 511)], red[0]);
        idx_f[(size_t)m * 2 + q] = (float)idx;
        idx_i[m * 2 + q] = (int)idx;
    }
}

// ---------------- quantized output (channel-major) via LDS transpose ----------------
__global__ void quant_out_kernel(const float* __restrict__ cb0, const float* __restrict__ cb1,
                                 const int* __restrict__ idxi, float* __restrict__ out4) {
    __shared__ float buf[64][129];
    __shared__ int i0s[64], i1s[64];
    int b = blockIdx.x;
    int t0 = blockIdx.y * 64;
    int c0 = blockIdx.z * 128;
    int tid = threadIdx.x;
    if (tid < 64) {
        int t = t0 + tid;
        int i0 = 0, i1 = 0;
        if (t < T4L) { i0 = idxi[(b * T4L + t) * 2]; i1 = idxi[(b * T4L + t) * 2 + 1]; }
        i0s[tid] = i0; i1s[tid] = i1;
    }
    __syncthreads();
    int cl = tid & 127, th = tid >> 7;
    for (int t = th; t < 64; t += 2) {
        if (t0 + t < T4L)
            buf[t][cl] = cb0[(size_t)i0s[t] * 512 + c0 + cl] + cb1[(size_t)i1s[t] * 512 + c0 + cl];
    }
    __syncthreads();
    int lane = tid & 63, ch = tid >> 6;
    for (int cc = ch; cc < 128; cc += 4) {
        int t = t0 + lane;
        if (t < T4L) out4[((size_t)b * 512 + c0 + cc) * T4L + t] = buf[lane][cc];
    }
}

// ---------------- final 1x1 conv + recon loss ----------------
__global__ void dec_final_kernel(const float* __restrict__ d2buf, const float* __restrict__ W,
                                 const float* __restrict__ bb, const float* __restrict__ img,
                                 float* __restrict__ out, float* __restrict__ slots) {
    __shared__ float red[256];
    int tok = blockIdx.x * 256 + threadIdx.x;   // 1632 blocks * 256 = 417792 exact
    float acc = bb[0];
    const float* row = d2buf + (size_t)tok * 64;
    #pragma unroll
    for (int i = 0; i < 16; ++i) {
        float4 v = *(const float4*)(row + i * 4);
        float4 w = *(const float4*)(W + i * 4);
        acc += v.x * w.x + v.y * w.y + v.z * w.z + v.w * w.w;
    }
    out[tok] = acc;
    float d = img[tok] - acc;
    red[threadIdx.x] = d * d; __syncthreads();
    for (int s = 128; s > 0; s >>= 1) { if (threadIdx.x < s) red[threadIdx.x] += red[threadIdx.x + s]; __syncthreads(); }
    if (threadIdx.x == 0) atomicAdd(&slots[blockIdx.x & 511], red[0]);
}

// ---------------- finalize losses ----------------
__global__ void finalize_kernel(const float* __restrict__ slots, float* __restrict__ out_scalars) {
    __shared__ float red[256];
    int tid = threadIdx.x;
    for (int which = 0; which < 3; ++which) {
        float s = slots[which * 512 + tid] + slots[which * 512 + tid + 256];
        red[tid] = s; __syncthreads();
        for (int st = 128; st > 0; st >>= 1) { if (tid < st) red[tid] += red[tid + st]; __syncthreads(); }
        if (tid == 0) {
            float denom = (which == 0) ? (float)MOUT : (float)((size_t)MTOK * 512);
            out_scalars[which] = red[0] / denom;
        }
        __syncthreads();
    }
}

// ---------------- launch ----------------
extern "C" void kernel_launch(void* const* d_in, const int* in_sizes, int n_in,
                              void* d_out, int out_size, void* d_ws, size_t ws_size,
                              hipStream_t stream) {
    const float* img  = (const float*)d_in[0];
    const float* We1  = (const float*)d_in[1];
    const float* be1  = (const float*)d_in[2];
    const float* We2  = (const float*)d_in[3];
    const float* be2  = (const float*)d_in[4];
    const float* We3  = (const float*)d_in[5];
    const float* be3  = (const float*)d_in[6];
    const float* cbs  = (const float*)d_in[7];   // [2,1024,512]
    const float* Wtd1 = (const float*)d_in[8];
    const float* bd1  = (const float*)d_in[9];
    const float* Wtd2 = (const float*)d_in[10];
    const float* bd2  = (const float*)d_in[11];
    const float* Wd3  = (const float*)d_in[12];
    const float* bd3  = (const float*)d_in[13];

    float* w = (float*)d_ws;
    float* xr   = w + OFF_XR;        // tokens / residual; later reused as d2buf
    float* h1   = w + OFF_H1;        // later reused as d1
    float* h2   = w + OFF_H2;
    float* Be2  = w + OFF_BE2;
    float* Bd1  = w + OFF_BD1;
    float* Bd2  = w + OFF_BD2;
    float* bx1  = w + OFF_BX1;
    float* bx2  = w + OFF_BX2;
    float* c2   = w + OFF_C2;
    float* r2   = w + OFF_R2;
    float* slots= w + OFF_SLOT;
    int*   idxi = (int*)(w + OFF_IDXI);
    unsigned long long* keys = (unsigned long long*)(w + OFF_KEYS);

    float* outp = (float*)d_out;
    float* out0   = outp + DO_OUT;
    float* oscal  = outp + DO_RECON;    // recon, commit0, commit1 contiguous
    float* idxf   = outp + DO_IDX;
    float* qout   = outp + DO_QUANT;

    // init: argmin keys to +inf, loss slots to zero
    hipMemsetAsync(keys, 0xFF, 2 * (size_t)MTOK * sizeof(unsigned long long), stream);
    hipMemsetAsync(slots, 0, 1536 * sizeof(float), stream);

    prep_kernel<<<64, 256, 0, stream>>>(We2, Wtd1, Wtd2, bd1, bd2, Be2, Bd1, Bd2, bx1, bx2);
    rownorm_kernel<<<(2048 * 64) / 256, 256, 0, stream>>>(cbs, c2, 2048);

    // encoder
    enc1_kernel<<<(NB * T2L * HIDC) / 256, 256, 0, stream>>>(img, We1, be1, h1);
    gemm_nt<<<dim3(MTOK / 128, 1), 256, 0, stream>>>(h1, Be2, be2, h2, MTOK, 64, 128, 1, 0, 1);
    gemm_nt<<<dim3(MTOK / 128, 8), 256, 0, stream>>>(h2, We3, be3, xr, MTOK, 512, 64, 0, 0, 0);
    rownorm_kernel<<<((size_t)MTOK * 64) / 256, 256, 0, stream>>>(xr, r2, MTOK);

    // residual VQ, q = 0
    vq_gemm_argmin<<<dim3(MTOK / 128, 16), 256, 0, stream>>>(xr, cbs, c2, r2, keys);
    vq_apply<<<MTOK, 256, 0, stream>>>(cbs, keys, xr, r2, idxf, idxi, slots, 0, 1);
    // q = 1
    vq_gemm_argmin<<<dim3(MTOK / 128, 16), 256, 0, stream>>>(xr, cbs + (size_t)NTOK * CBD, c2 + NTOK, r2, keys + MTOK);
    vq_apply<<<MTOK, 256, 0, stream>>>(cbs + (size_t)NTOK * CBD, keys + MTOK, xr, r2, idxf, idxi, slots, 1, 0);

    // quantized output [B,512,408]
    quant_out_kernel<<<dim3(NB, 7, 4), 256, 0, stream>>>(cbs, cbs + (size_t)NTOK * CBD, idxi, qout);

    // decoder: convT1 (A = quantized channel-major), d1 reuses h1 region
    gemm_nt<<<dim3(MTOK / 128, 2), 256, 0, stream>>>(qout, Bd1, bx1, h1, MTOK, 128, 512, 2, 1, 1);
    // convT2: d2buf reuses xr region
    gemm_nt<<<dim3(M2TOK / 128, 2), 256, 0, stream>>>(h1, Bd2, bx2, xr, M2TOK, 128, 64, 0, 2, 1);
    // final 1x1 + recon loss
    dec_final_kernel<<<MOUT / 256, 256, 0, stream>>>(xr, Wd3, bd3, img, out0, slots);

    finalize_kernel<<<1, 256, 0, stream>>>(slots, oscal);
}

// Round 2
// 3370.409 us; speedup vs baseline: 1.1029x; 1.1029x over previous
//
#include <hip/hip_runtime.h>

// ---------------- problem constants ----------------
#define NB    256
#define TLEN  1632
#define HIDC  64
#define CBD   512
#define NTOK  1024
#define T2L   816          // after enc conv1
#define T4L   408          // after enc conv2 (token count per batch)
#define MTOK  (NB*T4L)     // 104448 tokens
#define M2TOK (NB*T2L)     // 208896
#define MOUT  (NB*TLEN)    // 417792

// d_out flat offsets (floats)
#define DO_OUT    ((size_t)0)
#define DO_RECON  ((size_t)417792)
#define DO_COMMIT ((size_t)417793)
#define DO_IDX    ((size_t)417795)
#define DO_QUANT  ((size_t)626691)

// ---------------- workspace layout (float indices) ----------------
static constexpr size_t N_XR   = (size_t)MTOK * CBD;        // 53,477,376 (xr/residual; later d2buf)
static constexpr size_t OFF_XR = 0;
static constexpr size_t OFF_H1 = OFF_XR + N_XR;             // h1, later d1  [256*816*64]
static constexpr size_t N_H1   = (size_t)NB * T2L * HIDC;
static constexpr size_t OFF_H2 = OFF_H1 + N_H1;             // h2 [256*408*64]
static constexpr size_t N_H2   = (size_t)NB * T4L * HIDC;
static constexpr size_t OFF_BE2 = OFF_H2 + N_H2;            // 64*128
static constexpr size_t OFF_BD1 = OFF_BE2 + 8192;           // 128*512
static constexpr size_t OFF_BD2 = OFF_BD1 + 65536;          // 128*64
static constexpr size_t OFF_BX1 = OFF_BD2 + 8192;           // 128 expanded bias d1
static constexpr size_t OFF_BX2 = OFF_BX1 + 128;            // 128 expanded bias d2
static constexpr size_t OFF_C2  = OFF_BX2 + 128;            // 2048 codebook norms
static constexpr size_t OFF_R2  = OFF_C2 + 2048;            // 104448 token norms
static constexpr size_t OFF_SLOT= OFF_R2 + MTOK;            // 1536 loss slots (recon, c0, c1)
static constexpr size_t OFF_IDXI= OFF_SLOT + 1536;          // 104448*2 ints
static constexpr size_t OFF_KEYS= OFF_IDXI + (size_t)MTOK*2;// 2*104448 u64 (even float offset -> 8B aligned)

// ---------------- helpers ----------------
__device__ inline unsigned long long shfl_xor_u64_w16(unsigned long long v, int m) {
    unsigned lo = (unsigned)v, hi = (unsigned)(v >> 32);
    lo = __shfl_xor(lo, m, 16);
    hi = __shfl_xor(hi, m, 16);
    return (((unsigned long long)hi) << 32) | lo;
}

// ---------------- weight prep ----------------
__global__ void prep_kernel(const float* __restrict__ We2, const float* __restrict__ Wtd1,
                            const float* __restrict__ Wtd2, const float* __restrict__ bd1,
                            const float* __restrict__ bd2,
                            float* __restrict__ Be2, float* __restrict__ Bd1,
                            float* __restrict__ Bd2, float* __restrict__ bx1, float* __restrict__ bx2) {
    int i = blockIdx.x * blockDim.x + threadIdx.x;
    int stride = gridDim.x * blockDim.x;
    // Be2[c][k], k = tap*64 + ch  ->  We2[c][ch][tap]
    for (int x = i; x < 64 * 128; x += stride) {
        int c = x >> 7, k = x & 127;
        Be2[x] = We2[c * 128 + ((k & 63) << 1) + (k >> 6)];
    }
    // Bd1[n][k] = Wtd1[k*128 + n]   (n = co*2+tap, k = ci)
    for (int x = i; x < 128 * 512; x += stride) {
        int n = x >> 9, k = x & 511;
        Bd1[x] = Wtd1[k * 128 + n];
    }
    // Bd2[n][k] = Wtd2[k*128 + n]
    for (int x = i; x < 128 * 64; x += stride) {
        int n = x >> 6, k = x & 63;
        Bd2[x] = Wtd2[k * 128 + n];
    }
    for (int x = i; x < 128; x += stride) { bx1[x] = bd1[x >> 1]; bx2[x] = bd2[x >> 1]; }
}

// ---------------- row sum-of-squares (512-wide rows): one wave per row ----------------
__global__ void rownorm_kernel(const float* __restrict__ X, float* __restrict__ out, int rows) {
    int w = (blockIdx.x * blockDim.x + threadIdx.x) >> 6;
    int lane = threadIdx.x & 63;
    if (w >= rows) return;
    const float* r = X + (size_t)w * 512;
    float4 a = *(const float4*)(r + lane * 8);
    float4 b = *(const float4*)(r + lane * 8 + 4);
    float s = a.x*a.x + a.y*a.y + a.z*a.z + a.w*a.w + b.x*b.x + b.y*b.y + b.z*b.z + b.w*b.w;
    #pragma unroll
    for (int o = 32; o > 0; o >>= 1) s += __shfl_down(s, o, 64);
    if (lane == 0) out[w] = s;
}

// ---------------- encoder conv1 (Cin=1, k2s2) -> h1 token-major [b][t][c] ----------------
__global__ void enc1_kernel(const float* __restrict__ img, const float* __restrict__ W,
                            const float* __restrict__ bias, float* __restrict__ h1) {
    int idx = blockIdx.x * 256 + threadIdx.x;          // over 256*816*64
    int c = idx & 63;
    int t = (idx >> 6) % T2L;
    int b = idx / (64 * T2L);
    float v = W[c * 2] * img[(size_t)b * TLEN + 2 * t] +
              W[c * 2 + 1] * img[(size_t)b * TLEN + 2 * t + 1] + bias[c];
    h1[idx] = fmaxf(v, 0.f);
}

// ---------------- generic NT SGEMM: C[M,N] = A[M,K] . B[N,K]^T + bias ----------------
// tile 128(M) x 64(N), K-chunk 32, 256 threads, 8x4 microtile
// amode: 0 plain row-major A (ld=K); 1 e2 concat-token view of h1; 2 channel-major quantized
// cmode: 0 C[m*N+n]; 1 convT1 interleave (Tin=408); 2 convT2 interleave (Tin=816)
__global__ __launch_bounds__(256) void gemm_nt(const float* __restrict__ A, const float* __restrict__ Bw,
                        const float* __restrict__ bias, float* __restrict__ C,
                        int M, int N, int K, int amode, int cmode, int relu) {
    __shared__ float As[32][132];
    __shared__ float Bs[32][68];
    int m0 = blockIdx.x * 128;
    int n0 = blockIdx.y * 64;
    int tid = threadIdx.x;
    int tx = tid & 15;
    int ty = tid >> 4;
    float acc[8][4];
    #pragma unroll
    for (int i = 0; i < 8; ++i)
        #pragma unroll
        for (int j = 0; j < 4; ++j) acc[i][j] = 0.f;

    for (int k0 = 0; k0 < K; k0 += 32) {
        if (amode != 2) {
            #pragma unroll
            for (int i = 0; i < 4; ++i) {
                int idx = tid + i * 256;           // 0..1023
                int row = idx >> 3;
                int kq = idx & 7;
                int m = m0 + row;
                size_t base;
                if (amode == 0) base = (size_t)m * K;
                else            base = (size_t)(((m / T4L) * T2L + 2 * (m % T4L)) * 64);
                float4 v = *(const float4*)(A + base + k0 + kq * 4);
                int kk = kq * 4;
                As[kk + 0][row] = v.x; As[kk + 1][row] = v.y;
                As[kk + 2][row] = v.z; As[kk + 3][row] = v.w;
            }
        } else {
            // quantized channel-major: addr = ((m/408)*512 + k)*408 + (m%408)
            int ml = tid & 127;
            int kl = tid >> 7;                     // 0..1
            int m = m0 + ml;
            int b = m / T4L, t = m % T4L;
            size_t rowbase = ((size_t)b * 512) * T4L + t;
            for (int kk = kl; kk < 32; kk += 2)
                As[kk][ml] = A[rowbase + (size_t)(k0 + kk) * T4L];
        }
        #pragma unroll
        for (int i = 0; i < 2; ++i) {
            int idx = tid + i * 256;               // 0..511
            int row = idx >> 3;
            int kq = idx & 7;
            float4 v = *(const float4*)(Bw + (size_t)(n0 + row) * K + k0 + kq * 4);
            int kk = kq * 4;
            Bs[kk + 0][row] = v.x; Bs[kk + 1][row] = v.y;
            Bs[kk + 2][row] = v.z; Bs[kk + 3][row] = v.w;
        }
        __syncthreads();
        #pragma unroll
        for (int kk = 0; kk < 32; ++kk) {
            float a[8], bf[4];
            float4 a0 = *(const float4*)&As[kk][ty * 8];
            float4 a1 = *(const float4*)&As[kk][ty * 8 + 4];
            a[0]=a0.x; a[1]=a0.y; a[2]=a0.z; a[3]=a0.w;
            a[4]=a1.x; a[5]=a1.y; a[6]=a1.z; a[7]=a1.w;
            float4 b0 = *(const float4*)&Bs[kk][tx * 4];
            bf[0]=b0.x; bf[1]=b0.y; bf[2]=b0.z; bf[3]=b0.w;
            #pragma unroll
            for (int i = 0; i < 8; ++i)
                #pragma unroll
                for (int j = 0; j < 4; ++j) acc[i][j] += a[i] * bf[j];
        }
        __syncthreads();
    }
    // epilogue
    #pragma unroll
    for (int i = 0; i < 8; ++i) {
        int m = m0 + ty * 8 + i;
        if (cmode == 0) {
            float4 v;
            float b0 = bias[n0 + tx * 4 + 0], b1 = bias[n0 + tx * 4 + 1];
            float b2 = bias[n0 + tx * 4 + 2], b3 = bias[n0 + tx * 4 + 3];
            v.x = acc[i][0] + b0; v.y = acc[i][1] + b1;
            v.z = acc[i][2] + b2; v.w = acc[i][3] + b3;
            if (relu) { v.x=fmaxf(v.x,0.f); v.y=fmaxf(v.y,0.f); v.z=fmaxf(v.z,0.f); v.w=fmaxf(v.w,0.f); }
            *(float4*)(C + (size_t)m * N + n0 + tx * 4) = v;
        } else {
            int Tin = (cmode == 1) ? T4L : T2L;
            int Texp = 2 * Tin;
            int bb = m / Tin, t = m % Tin;
            #pragma unroll
            for (int j = 0; j < 4; ++j) {
                int n = n0 + tx * 4 + j;
                float v = acc[i][j] + bias[n];
                if (relu) v = fmaxf(v, 0.f);
                size_t off = (size_t)((bb * Texp + 2 * t + (n & 1)) * 64 + (n >> 1));
                C[off] = v;
            }
        }
    }
}

// ---------------- VQ distance GEMM + argmin epilogue (128x128 tile, 8x8 microtile) ----------------
// A = residual [MTOK,512], B = cb [1024,512]; d2 = (r2 - 2*dot) + c2; key=(map(d2)<<32)|n
// Staging: register transpose -> b128 LDS writes (conflict-free at BW minimum).
__global__ __launch_bounds__(256) void vq_gemm_argmin(const float* __restrict__ A, const float* __restrict__ cb,
                               const float* __restrict__ c2, const float* __restrict__ r2,
                               unsigned long long* __restrict__ keybuf) {
    __shared__ float As[32][132];
    __shared__ float Bs[32][132];
    int m0 = blockIdx.x * 128;
    int n0 = blockIdx.y * 128;
    int tid = threadIdx.x;
    int tx = tid & 15;
    int ty = tid >> 4;
    int kq = tid & 7;         // staging k-quad 0..7
    int rq = tid >> 3;        // staging row-quad 0..31
    float acc[8][8];
    #pragma unroll
    for (int i = 0; i < 8; ++i)
        #pragma unroll
        for (int j = 0; j < 4; ++j) { acc[i][j] = 0.f; acc[i][j + 4] = 0.f; }

    const float* Abase = A  + (size_t)(m0 + rq * 4) * 512 + kq * 4;
    const float* Bbase = cb + (size_t)(n0 + rq * 4) * 512 + kq * 4;

    for (int k0 = 0; k0 < 512; k0 += 32) {
        float4 va[4], vb[4];
        #pragma unroll
        for (int j = 0; j < 4; ++j) {
            va[j] = *(const float4*)(Abase + (size_t)j * 512 + k0);
            vb[j] = *(const float4*)(Bbase + (size_t)j * 512 + k0);
        }
        __syncthreads();                       // previous compute done before overwrite
        const float* vaf = (const float*)va;
        const float* vbf = (const float*)vb;
        #pragma unroll
        for (int c = 0; c < 4; ++c) {
            float4 wa; wa.x = vaf[c]; wa.y = vaf[4 + c]; wa.z = vaf[8 + c]; wa.w = vaf[12 + c];
            float4 wb; wb.x = vbf[c]; wb.y = vbf[4 + c]; wb.z = vbf[8 + c]; wb.w = vbf[12 + c];
            *(float4*)&As[kq * 4 + c][rq * 4] = wa;
            *(float4*)&Bs[kq * 4 + c][rq * 4] = wb;
        }
        __syncthreads();
        #pragma unroll
        for (int kk = 0; kk < 32; ++kk) {
            float4 a0 = *(const float4*)&As[kk][ty * 4];
            float4 a1 = *(const float4*)&As[kk][64 + ty * 4];
            float4 b0 = *(const float4*)&Bs[kk][tx * 4];
            float4 b1 = *(const float4*)&Bs[kk][64 + tx * 4];
            float a[8] = {a0.x, a0.y, a0.z, a0.w, a1.x, a1.y, a1.z, a1.w};
            float b[8] = {b0.x, b0.y, b0.z, b0.w, b1.x, b1.y, b1.z, b1.w};
            #pragma unroll
            for (int i = 0; i < 8; ++i)
                #pragma unroll
                for (int j = 0; j < 8; ++j) acc[i][j] += a[i] * b[j];
        }
    }
    // argmin epilogue: min over this block's 128 codes per token, merge globally
    #pragma unroll
    for (int i = 0; i < 8; ++i) {
        int m = m0 + ((i < 4) ? (ty * 4 + i) : (64 + ty * 4 + i - 4));
        float rr = r2[m];
        unsigned long long best = ~0ull;
        #pragma unroll
        for (int j = 0; j < 8; ++j) {
            int n = n0 + ((j < 4) ? (tx * 4 + j) : (64 + tx * 4 + j - 4));
            float d2 = (rr - 2.0f * acc[i][j]) + c2[n];
            unsigned u = __float_as_uint(d2);
            u = (u & 0x80000000u) ? ~u : (u | 0x80000000u);   // monotonic map
            unsigned long long key = (((unsigned long long)u) << 32) | (unsigned)n;
            if (key < best) best = key;
        }
        #pragma unroll
        for (int s = 1; s < 16; s <<= 1) {
            unsigned long long o = shfl_xor_u64_w16(best, s);
            if (o < best) best = o;
        }
        if (tx == 0) atomicMin(&keybuf[m], best);
    }
}

// ---------------- VQ apply: residual update, commit partial, indices ----------------
__global__ void vq_apply(const float* __restrict__ cb, const unsigned long long* __restrict__ keybuf,
                         float* __restrict__ R, float* __restrict__ r2,
                         float* __restrict__ idx_f, int* __restrict__ idx_i,
                         float* __restrict__ slots, int q, int write_r) {
    __shared__ float red[256];
    int m = blockIdx.x;
    int tid = threadIdx.x;
    unsigned idx = (unsigned)(keybuf[m] & 0xFFFFFFFFull);
    const float* c = cb + (size_t)idx * 512;
    float* r = R + (size_t)m * 512;
    float s = 0.f;
    for (int c0 = tid; c0 < 512; c0 += 256) {
        float nr = r[c0] - c[c0];
        if (write_r) r[c0] = nr;
        s += nr * nr;
    }
    red[tid] = s; __syncthreads();
    for (int st = 128; st > 0; st >>= 1) { if (tid < st) red[tid] += red[tid + st]; __syncthreads(); }
    if (tid == 0) {
        if (write_r) r2[m] = red[0];
        atomicAdd(&slots[512 + q * 512 + (m & 511)], red[0]);
        idx_f[(size_t)m * 2 + q] = (float)idx;
        idx_i[m * 2 + q] = (int)idx;
    }
}

// ---------------- quantized output (channel-major) via LDS transpose ----------------
__global__ void quant_out_kernel(const float* __restrict__ cb0, const float* __restrict__ cb1,
                                 const int* __restrict__ idxi, float* __restrict__ out4) {
    __shared__ float buf[64][129];
    __shared__ int i0s[64], i1s[64];
    int b = blockIdx.x;
    int t0 = blockIdx.y * 64;
    int c0 = blockIdx.z * 128;
    int tid = threadIdx.x;
    if (tid < 64) {
        int t = t0 + tid;
        int i0 = 0, i1 = 0;
        if (t < T4L) { i0 = idxi[(b * T4L + t) * 2]; i1 = idxi[(b * T4L + t) * 2 + 1]; }
        i0s[tid] = i0; i1s[tid] = i1;
    }
    __syncthreads();
    int cl = tid & 127, th = tid >> 7;
    for (int t = th; t < 64; t += 2) {
        if (t0 + t < T4L)
            buf[t][cl] = cb0[(size_t)i0s[t] * 512 + c0 + cl] + cb1[(size_t)i1s[t] * 512 + c0 + cl];
    }
    __syncthreads();
    int lane = tid & 63, ch = tid >> 6;
    for (int cc = ch; cc < 128; cc += 4) {
        int t = t0 + lane;
        if (t < T4L) out4[((size_t)b * 512 + c0 + cc) * T4L + t] = buf[lane][cc];
    }
}

// ---------------- final 1x1 conv + recon loss ----------------
__global__ void dec_final_kernel(const float* __restrict__ d2buf, const float* __restrict__ W,
                                 const float* __restrict__ bb, const float* __restrict__ img,
                                 float* __restrict__ out, float* __restrict__ slots) {
    __shared__ float red[256];
    int tok = blockIdx.x * 256 + threadIdx.x;   // 1632 blocks * 256 = 417792 exact
    float acc = bb[0];
    const float* row = d2buf + (size_t)tok * 64;
    #pragma unroll
    for (int i = 0; i < 16; ++i) {
        float4 v = *(const float4*)(row + i * 4);
        float4 w = *(const float4*)(W + i * 4);
        acc += v.x * w.x + v.y * w.y + v.z * w.z + v.w * w.w;
    }
    out[tok] = acc;
    float d = img[tok] - acc;
    red[threadIdx.x] = d * d; __syncthreads();
    for (int s = 128; s > 0; s >>= 1) { if (threadIdx.x < s) red[threadIdx.x] += red[threadIdx.x + s]; __syncthreads(); }
    if (threadIdx.x == 0) atomicAdd(&slots[blockIdx.x & 511], red[0]);
}

// ---------------- finalize losses ----------------
__global__ void finalize_kernel(const float* __restrict__ slots, float* __restrict__ out_scalars) {
    __shared__ float red[256];
    int tid = threadIdx.x;
    for (int which = 0; which < 3; ++which) {
        float s = slots[which * 512 + tid] + slots[which * 512 + tid + 256];
        red[tid] = s; __syncthreads();
        for (int st = 128; st > 0; st >>= 1) { if (tid < st) red[tid] += red[tid + st]; __syncthreads(); }
        if (tid == 0) {
            float denom = (which == 0) ? (float)MOUT : (float)((size_t)MTOK * 512);
            out_scalars[which] = red[0] / denom;
        }
        __syncthreads();
    }
}

// ---------------- launch ----------------
extern "C" void kernel_launch(void* const* d_in, const int* in_sizes, int n_in,
                              void* d_out, int out_size, void* d_ws, size_t ws_size,
                              hipStream_t stream) {
    const float* img  = (const float*)d_in[0];
    const float* We1  = (const float*)d_in[1];
    const float* be1  = (const float*)d_in[2];
    const float* We2  = (const float*)d_in[3];
    const float* be2  = (const float*)d_in[4];
    const float* We3  = (const float*)d_in[5];
    const float* be3  = (const float*)d_in[6];
    const float* cbs  = (const float*)d_in[7];   // [2,1024,512]
    const float* Wtd1 = (const float*)d_in[8];
    const float* bd1  = (const float*)d_in[9];
    const float* Wtd2 = (const float*)d_in[10];
    const float* bd2  = (const float*)d_in[11];
    const float* Wd3  = (const float*)d_in[12];
    const float* bd3  = (const float*)d_in[13];

    float* w = (float*)d_ws;
    float* xr   = w + OFF_XR;        // tokens / residual; later reused as d2buf
    float* h1   = w + OFF_H1;        // later reused as d1
    float* h2   = w + OFF_H2;
    float* Be2  = w + OFF_BE2;
    float* Bd1  = w + OFF_BD1;
    float* Bd2  = w + OFF_BD2;
    float* bx1  = w + OFF_BX1;
    float* bx2  = w + OFF_BX2;
    float* c2   = w + OFF_C2;
    float* r2   = w + OFF_R2;
    float* slots= w + OFF_SLOT;
    int*   idxi = (int*)(w + OFF_IDXI);
    unsigned long long* keys = (unsigned long long*)(w + OFF_KEYS);

    float* outp = (float*)d_out;
    float* out0   = outp + DO_OUT;
    float* oscal  = outp + DO_RECON;    // recon, commit0, commit1 contiguous
    float* idxf   = outp + DO_IDX;
    float* qout   = outp + DO_QUANT;

    // init: argmin keys to +inf, loss slots to zero
    hipMemsetAsync(keys, 0xFF, 2 * (size_t)MTOK * sizeof(unsigned long long), stream);
    hipMemsetAsync(slots, 0, 1536 * sizeof(float), stream);

    prep_kernel<<<64, 256, 0, stream>>>(We2, Wtd1, Wtd2, bd1, bd2, Be2, Bd1, Bd2, bx1, bx2);
    rownorm_kernel<<<(2048 * 64) / 256, 256, 0, stream>>>(cbs, c2, 2048);

    // encoder
    enc1_kernel<<<(NB * T2L * HIDC) / 256, 256, 0, stream>>>(img, We1, be1, h1);
    gemm_nt<<<dim3(MTOK / 128, 1), 256, 0, stream>>>(h1, Be2, be2, h2, MTOK, 64, 128, 1, 0, 1);
    gemm_nt<<<dim3(MTOK / 128, 8), 256, 0, stream>>>(h2, We3, be3, xr, MTOK, 512, 64, 0, 0, 0);
    rownorm_kernel<<<((size_t)MTOK * 64) / 256, 256, 0, stream>>>(xr, r2, MTOK);

    // residual VQ, q = 0
    vq_gemm_argmin<<<dim3(MTOK / 128, 8), 256, 0, stream>>>(xr, cbs, c2, r2, keys);
    vq_apply<<<MTOK, 256, 0, stream>>>(cbs, keys, xr, r2, idxf, idxi, slots, 0, 1);
    // q = 1
    vq_gemm_argmin<<<dim3(MTOK / 128, 8), 256, 0, stream>>>(xr, cbs + (size_t)NTOK * CBD, c2 + NTOK, r2, keys + MTOK);
    vq_apply<<<MTOK, 256, 0, stream>>>(cbs + (size_t)NTOK * CBD, keys + MTOK, xr, r2, idxf, idxi, slots, 1, 0);

    // quantized output [B,512,408]
    quant_out_kernel<<<dim3(NB, 7, 4), 256, 0, stream>>>(cbs, cbs + (size_t)NTOK * CBD, idxi, qout);

    // decoder: convT1 (A = quantized channel-major), d1 reuses h1 region
    gemm_nt<<<dim3(MTOK / 128, 2), 256, 0, stream>>>(qout, Bd1, bx1, h1, MTOK, 128, 512, 2, 1, 1);
    // convT2: d2buf reuses xr region
    gemm_nt<<<dim3(M2TOK / 128, 2), 256, 0, stream>>>(h1, Bd2, bx2, xr, M2TOK, 128, 64, 0, 2, 1);
    // final 1x1 + recon loss
    dec_final_kernel<<<MOUT / 256, 256, 0, stream>>>(xr, Wd3, bd3, img, out0, slots);

    finalize_kernel<<<1, 256, 0, stream>>>(slots, oscal);
}